// Round 1
// 5553.975 us; speedup vs baseline: 1.2323x; 1.2323x over previous
//
#include <hip/hip_runtime.h>

// ---------------- problem constants ----------------
constexpr int TT   = 2048;   // tokens
constexpr int DD   = 768;    // model dim
constexpr int NH   = 12;     // heads
constexpr int NE   = 8;      // experts
constexpr int DFF  = 3072;   // ffn dim
constexpr int NV   = 32000;  // vocab
constexpr int S1R  = 129;    // global seq len (1 + 2048/16)
constexpr int QKVLD = 3 * DD; // 2304

constexpr int BM = 64, BN = 64, BK = 16;

typedef __attribute__((ext_vector_type(8))) short bf16x8;
typedef __attribute__((ext_vector_type(4))) float f32x4;

__device__ __forceinline__ float gelu_f(float v) {
  return 0.5f * v * (1.0f + erff(v * 0.70710678118654752f));
}

__device__ __forceinline__ ushort f2bf(float f) {
  unsigned u = __float_as_uint(f);
  u = (u + 0x7fffu + ((u >> 16) & 1u)) >> 16;   // round-to-nearest-even
  return (ushort)u;
}

__device__ __forceinline__ void gload_lds16(const void* g, void* l) {
  __builtin_amdgcn_global_load_lds(
      (const __attribute__((address_space(1))) unsigned int*)g,
      (__attribute__((address_space(3))) unsigned int*)l, 16, 0, 0);
}

// ---------------- elementwise ----------------
__global__ void add_pos_kernel(const float* __restrict__ xe, const float* __restrict__ pe,
                               float* __restrict__ X, int n) {
  int i = blockIdx.x * blockDim.x + threadIdx.x;
  if (i < n) X[i] = xe[i] + pe[i];
}

__global__ void zero_i32(int* p, int n) {
  int i = blockIdx.x * blockDim.x + threadIdx.x;
  if (i < n) p[i] = 0;
}
__global__ void zero_f32(float* p, int n) {
  int i = blockIdx.x * blockDim.x + threadIdx.x;
  if (i < n) p[i] = 0.f;
}

// cast fp32 -> bf16, 4 elems/thread (n must be multiple of 4)
__global__ __launch_bounds__(256)
void cast_bf16_kernel(const float* __restrict__ in, ushort* __restrict__ out, int n) {
  int i = (blockIdx.x * blockDim.x + threadIdx.x) * 4;
  if (i >= n) return;
  float4 v = *(const float4*)(in + i);
  ushort4 o;
  o.x = f2bf(v.x); o.y = f2bf(v.y); o.z = f2bf(v.z); o.w = f2bf(v.w);
  *(ushort4*)(out + i) = o;
}

// ---------------- layernorm (1 block / row, D=768=3*256) ----------------
__global__ __launch_bounds__(256)
void ln_kernel(const float* __restrict__ Xin, const float* __restrict__ s,
               const float* __restrict__ b, float* __restrict__ Y, int rows) {
  int t = blockIdx.x;
  if (t >= rows) return;
  const float* xr = Xin + (size_t)t * DD;
  int tid = threadIdx.x;
  float x0 = xr[tid], x1 = xr[tid + 256], x2 = xr[tid + 512];
  __shared__ float red[256];
  red[tid] = x0 + x1 + x2;
  __syncthreads();
  for (int k = 128; k > 0; k >>= 1) { if (tid < k) red[tid] += red[tid + k]; __syncthreads(); }
  float mean = red[0] * (1.f / 768.f);
  __syncthreads();
  float d0 = x0 - mean, d1 = x1 - mean, d2 = x2 - mean;
  red[tid] = d0 * d0 + d1 * d1 + d2 * d2;
  __syncthreads();
  for (int k = 128; k > 0; k >>= 1) { if (tid < k) red[tid] += red[tid + k]; __syncthreads(); }
  float inv = 1.f / sqrtf(red[0] * (1.f / 768.f) + 1e-5f);
  float* yr = Y + (size_t)t * DD;
  yr[tid]       = d0 * inv * s[tid]       + b[tid];
  yr[tid + 256] = d1 * inv * s[tid + 256] + b[tid + 256];
  yr[tid + 512] = d2 * inv * s[tid + 512] + b[tid + 512];
}

// ---------------- generic tiled GEMM: C[M,N] (+)= A[M,K] @ W[N,K]^T + bias ----------------
template <bool ADD_C>
__global__ __launch_bounds__(256)
void gemm_tn(const float* __restrict__ A, const float* __restrict__ W,
             const float* __restrict__ bias, float* __restrict__ C,
             int M, int N, int Kd) {
  __shared__ float As[BK][BM + 4];
  __shared__ float Ws[BK][BN + 4];
  int n0 = blockIdx.x * BN, m0 = blockIdx.y * BM;
  int tid = threadIdx.x;
  int tx = tid & 15, ty = tid >> 4;
  int lrow = tid >> 2, lk4 = (tid & 3) * 4;
  float acc[4][4] = {};
  for (int k0 = 0; k0 < Kd; k0 += BK) {
    {
      int r = m0 + lrow;
      float4 v = (r < M) ? *(const float4*)(A + (size_t)r * Kd + k0 + lk4)
                         : make_float4(0.f, 0.f, 0.f, 0.f);
      As[lk4 + 0][lrow] = v.x; As[lk4 + 1][lrow] = v.y;
      As[lk4 + 2][lrow] = v.z; As[lk4 + 3][lrow] = v.w;
    }
    {
      int r = n0 + lrow;
      float4 v = (r < N) ? *(const float4*)(W + (size_t)r * Kd + k0 + lk4)
                         : make_float4(0.f, 0.f, 0.f, 0.f);
      Ws[lk4 + 0][lrow] = v.x; Ws[lk4 + 1][lrow] = v.y;
      Ws[lk4 + 2][lrow] = v.z; Ws[lk4 + 3][lrow] = v.w;
    }
    __syncthreads();
#pragma unroll
    for (int k = 0; k < BK; k++) {
      float a[4], b[4];
#pragma unroll
      for (int i = 0; i < 4; i++) a[i] = As[k][ty * 4 + i];
#pragma unroll
      for (int j = 0; j < 4; j++) b[j] = Ws[k][tx * 4 + j];
#pragma unroll
      for (int i = 0; i < 4; i++)
#pragma unroll
        for (int j = 0; j < 4; j++) acc[i][j] = fmaf(a[i], b[j], acc[i][j]);
    }
    __syncthreads();
  }
#pragma unroll
  for (int i = 0; i < 4; i++) {
    int r = m0 + ty * 4 + i;
    if (r >= M) continue;
#pragma unroll
    for (int j = 0; j < 4; j++) {
      int c = n0 + tx * 4 + j;
      if (c >= N) continue;
      float v = acc[i][j] + (bias ? bias[c] : 0.f);
      size_t idx = (size_t)r * N + c;
      if (ADD_C) C[idx] += v; else C[idx] = v;
    }
  }
}

// ---------------- bf16 MFMA GEMM for the LM head ----------------
// C[M,N] = A[M,K](bf16) @ W[N,K](bf16)^T, fp32 accum.
// 128x128 tile, BKH=64 K-step, 4 waves in 2x2 (each 64x64 via 4x4 frags of 16x16x32).
// LDS tiles [128 rows][64 bf16] with 16B-slot XOR swizzle: slot ^= (row & 7).
// Staged via global_load_lds width=16 (linear LDS dest + inverse-swizzled global src).
__global__ __launch_bounds__(256)
void head_gemm_bf16(const ushort* __restrict__ A, const ushort* __restrict__ W,
                    float* __restrict__ C, int M, int N, int K) {
  __shared__ ushort As[128 * 64];   // 16 KiB
  __shared__ ushort Bs[128 * 64];   // 16 KiB
  int tid  = threadIdx.x;
  int lane = tid & 63, wid = tid >> 6;
  int wm = wid >> 1, wn = wid & 1;          // 2x2 wave grid
  int m0 = blockIdx.y * 128, n0 = blockIdx.x * 128;

  f32x4 acc[4][4] = {};

  int rl = lane & 15, cs = lane >> 4;       // fragment row / k-group

  for (int k0 = 0; k0 < K; k0 += 64) {
    // ---- stage A and B tiles (each 16 KiB = 16 wave-chunks of 1 KiB) ----
#pragma unroll
    for (int r = 0; r < 4; ++r) {
      int chunk = (r * 4 + wid) << 10;            // wave-uniform byte offset
      int o     = chunk + lane * 16;              // this lane's linear LDS byte
      int row   = o >> 7;                         // 128 B per row
      int slot  = ((o >> 4) & 7) ^ (row & 7);     // inverse-swizzled source slot
      gload_lds16(A + (size_t)(m0 + row) * K + k0 + slot * 8, (char*)As + chunk);
      gload_lds16(W + (size_t)(n0 + row) * K + k0 + slot * 8, (char*)Bs + chunk);
    }
    __syncthreads();   // drains vmcnt(0) before barrier

    // ---- fragments: a[mi][ks], b[ni][ks]; m/n = lane&15, k = (lane>>4)*8 (+32*ks) ----
    bf16x8 af[4][2], bfr[4][2];
#pragma unroll
    for (int mi = 0; mi < 4; ++mi) {
      int m = wm * 64 + mi * 16 + rl;
      int n = wn * 64 + mi * 16 + rl;
#pragma unroll
      for (int ks = 0; ks < 2; ++ks) {
        int sa = (ks * 4 + cs) ^ (m & 7);
        int sb = (ks * 4 + cs) ^ (n & 7);
        af[mi][ks]  = *(const bf16x8*)((const char*)As + m * 128 + sa * 16);
        bfr[mi][ks] = *(const bf16x8*)((const char*)Bs + n * 128 + sb * 16);
      }
    }
#pragma unroll
    for (int mi = 0; mi < 4; ++mi)
#pragma unroll
      for (int ni = 0; ni < 4; ++ni)
#pragma unroll
        for (int ks = 0; ks < 2; ++ks)
          acc[mi][ni] = __builtin_amdgcn_mfma_f32_16x16x32_bf16(
              af[mi][ks], bfr[ni][ks], acc[mi][ni], 0, 0, 0);
    __syncthreads();
  }

  // ---- epilogue: C/D layout col = lane&15, row = (lane>>4)*4 + reg ----
#pragma unroll
  for (int mi = 0; mi < 4; ++mi) {
    int row = m0 + wm * 64 + mi * 16 + cs * 4;
#pragma unroll
    for (int ni = 0; ni < 4; ++ni) {
      int col = n0 + wn * 64 + ni * 16 + rl;
      f32x4 v = acc[mi][ni];
#pragma unroll
      for (int r = 0; r < 4; ++r)
        C[(size_t)(row + r) * N + col] = v[r];
    }
  }
}

// ---------------- MoE expert GEMM 1: H1 = gelu(gather(X) @ w1[e]^T + b1[e]) ----------------
__global__ __launch_bounds__(256)
void moe_gemm1(const float* __restrict__ Xin, const float* __restrict__ W1,
               const float* __restrict__ B1, float* __restrict__ H1,
               const int* __restrict__ perm, const int* __restrict__ off) {
  __shared__ float As[BK][BM + 4];
  __shared__ float Ws[BK][BN + 4];
  int e = blockIdx.z;
  int mstart = off[e];
  int mcnt = off[e + 1] - mstart;
  int m0 = blockIdx.y * BM;
  if (m0 >= mcnt) return;
  int n0 = blockIdx.x * BN;
  const float* W = W1 + (size_t)e * DFF * DD;
  const float* bias = B1 + (size_t)e * DFF;
  int tid = threadIdx.x;
  int tx = tid & 15, ty = tid >> 4;
  int lrow = tid >> 2, lk4 = (tid & 3) * 4;
  int gm = m0 + lrow;
  const float* arow = (gm < mcnt) ? (Xin + (size_t)perm[mstart + gm] * DD) : nullptr;
  float acc[4][4] = {};
  for (int k0 = 0; k0 < DD; k0 += BK) {
    float4 va = arow ? *(const float4*)(arow + k0 + lk4) : make_float4(0.f, 0.f, 0.f, 0.f);
    As[lk4 + 0][lrow] = va.x; As[lk4 + 1][lrow] = va.y;
    As[lk4 + 2][lrow] = va.z; As[lk4 + 3][lrow] = va.w;
    int wr = n0 + lrow;
    float4 vw = *(const float4*)(W + (size_t)wr * DD + k0 + lk4);
    Ws[lk4 + 0][lrow] = vw.x; Ws[lk4 + 1][lrow] = vw.y;
    Ws[lk4 + 2][lrow] = vw.z; Ws[lk4 + 3][lrow] = vw.w;
    __syncthreads();
#pragma unroll
    for (int k = 0; k < BK; k++) {
      float a[4], b[4];
#pragma unroll
      for (int i = 0; i < 4; i++) a[i] = As[k][ty * 4 + i];
#pragma unroll
      for (int j = 0; j < 4; j++) b[j] = Ws[k][tx * 4 + j];
#pragma unroll
      for (int i = 0; i < 4; i++)
#pragma unroll
        for (int j = 0; j < 4; j++) acc[i][j] = fmaf(a[i], b[j], acc[i][j]);
    }
    __syncthreads();
  }
#pragma unroll
  for (int i = 0; i < 4; i++) {
    int r = m0 + ty * 4 + i;
    if (r >= mcnt) continue;
#pragma unroll
    for (int j = 0; j < 4; j++) {
      int c = n0 + tx * 4 + j;
      float v = acc[i][j] + bias[c];
      H1[(size_t)(mstart + r) * DFF + c] = gelu_f(v);
    }
  }
}

// ---------------- MoE expert GEMM 2: X[tok] += w * (H1 @ w2[e]^T + b2[e]) ----------------
__global__ __launch_bounds__(256)
void moe_gemm2(const float* __restrict__ H1, const float* __restrict__ W2,
               const float* __restrict__ B2, float* __restrict__ Xout,
               const int* __restrict__ perm, const int* __restrict__ off,
               const float* __restrict__ wlist) {
  __shared__ float As[BK][BM + 4];
  __shared__ float Ws[BK][BN + 4];
  int e = blockIdx.z;
  int mstart = off[e];
  int mcnt = off[e + 1] - mstart;
  int m0 = blockIdx.y * BM;
  if (m0 >= mcnt) return;
  int n0 = blockIdx.x * BN;
  const float* W = W2 + (size_t)e * DD * DFF;
  const float* bias = B2 + (size_t)e * DD;
  int tid = threadIdx.x;
  int tx = tid & 15, ty = tid >> 4;
  int lrow = tid >> 2, lk4 = (tid & 3) * 4;
  int gm = m0 + lrow;
  const float* arow = (gm < mcnt) ? (H1 + (size_t)(mstart + gm) * DFF) : nullptr;
  float acc[4][4] = {};
  for (int k0 = 0; k0 < DFF; k0 += BK) {
    float4 va = arow ? *(const float4*)(arow + k0 + lk4) : make_float4(0.f, 0.f, 0.f, 0.f);
    As[lk4 + 0][lrow] = va.x; As[lk4 + 1][lrow] = va.y;
    As[lk4 + 2][lrow] = va.z; As[lk4 + 3][lrow] = va.w;
    int wr = n0 + lrow;
    float4 vw = *(const float4*)(W + (size_t)wr * DFF + k0 + lk4);
    Ws[lk4 + 0][lrow] = vw.x; Ws[lk4 + 1][lrow] = vw.y;
    Ws[lk4 + 2][lrow] = vw.z; Ws[lk4 + 3][lrow] = vw.w;
    __syncthreads();
#pragma unroll
    for (int k = 0; k < BK; k++) {
      float a[4], b[4];
#pragma unroll
      for (int i = 0; i < 4; i++) a[i] = As[k][ty * 4 + i];
#pragma unroll
      for (int j = 0; j < 4; j++) b[j] = Ws[k][tx * 4 + j];
#pragma unroll
      for (int i = 0; i < 4; i++)
#pragma unroll
        for (int j = 0; j < 4; j++) acc[i][j] = fmaf(a[i], b[j], acc[i][j]);
    }
    __syncthreads();
  }
#pragma unroll
  for (int i = 0; i < 4; i++) {
    int r = m0 + ty * 4 + i;
    if (r >= mcnt) continue;
    int tok = perm[mstart + r];
    float sc = wlist[mstart + r];
#pragma unroll
    for (int j = 0; j < 4; j++) {
      int c = n0 + tx * 4 + j;
      float v = (acc[i][j] + bias[c]) * sc;
      atomicAdd(&Xout[(size_t)tok * DD + c], v);
    }
  }
}

// ---------------- attention: 1 block (64 threads) per (query, head) ----------------
__global__ __launch_bounds__(64)
void attn_kernel(const float* __restrict__ QKV, float* __restrict__ O, int Tlen) {
  int q = blockIdx.x, h = blockIdx.y;
  int tid = threadIdx.x;
  __shared__ float qv[64];
  __shared__ float sc[TT];
  qv[tid] = QKV[(size_t)q * QKVLD + h * 64 + tid];
  __syncthreads();
  int nk = q + 1;
  for (int k = tid; k < nk; k += 64) {
    const float* kr = QKV + (size_t)k * QKVLD + DD + h * 64;
    float s = 0.f;
#pragma unroll
    for (int d = 0; d < 64; d++) s = fmaf(qv[d], kr[d], s);
    sc[k] = s * 0.125f;
  }
  __syncthreads();
  float m = -1e30f;
  for (int k = tid; k < nk; k += 64) m = fmaxf(m, sc[k]);
#pragma unroll
  for (int o = 32; o > 0; o >>= 1) m = fmaxf(m, __shfl_down(m, o));
  m = __shfl(m, 0);
  float ssum = 0.f;
  for (int k = tid; k < nk; k += 64) {
    float e = __expf(sc[k] - m);
    sc[k] = e;
    ssum += e;
  }
#pragma unroll
  for (int o = 32; o > 0; o >>= 1) ssum += __shfl_down(ssum, o);
  ssum = __shfl(ssum, 0);
  float inv = 1.f / ssum;
  __syncthreads();
  float acc = 0.f;
  const float* vbase = QKV + 2 * DD + h * 64 + tid;
  for (int k = 0; k < nk; k++) acc = fmaf(sc[k], vbase[(size_t)k * QKVLD], acc);
  O[(size_t)q * DD + h * 64 + tid] = acc * inv;
}

// ---------------- router: logits, softmax, top-2, per-token weights ----------------
__global__ __launch_bounds__(64)
void router_kernel(const float* __restrict__ Hin, const float* __restrict__ RW,
                   const float* __restrict__ latent, const float* __restrict__ LRW,
                   int rows, int* __restrict__ selbuf, float* __restrict__ wbuf,
                   float* __restrict__ probbuf, int* __restrict__ cnt) {
  int t = blockIdx.x;
  if (t >= rows) return;
  int tid = threadIdx.x;
  const float* hr = Hin + (size_t)t * DD;
  __shared__ float logit[NE];
  for (int e = 0; e < NE; e++) {
    const float* w = RW + (size_t)e * DD;
    float p = 0.f;
    for (int d = tid; d < DD; d += 64) p = fmaf(hr[d], w[d], p);
    if (LRW) {
      const float* lw = LRW + (size_t)e * DD;
      for (int d = tid; d < DD; d += 64) p = fmaf(latent[d], lw[d], p);
    }
#pragma unroll
    for (int o = 32; o > 0; o >>= 1) p += __shfl_down(p, o);
    if (tid == 0) logit[e] = p;
  }
  __syncthreads();
  if (tid == 0) {
    float mx = logit[0];
    for (int e = 1; e < NE; e++) mx = fmaxf(mx, logit[e]);
    float pe[NE], ssum = 0.f;
    for (int e = 0; e < NE; e++) { pe[e] = __expf(logit[e] - mx); ssum += pe[e]; }
    float inv = 1.f / ssum;
    for (int e = 0; e < NE; e++) { pe[e] *= inv; probbuf[(size_t)t * NE + e] = pe[e]; }
    int e0 = 0;
    for (int e = 1; e < NE; e++) if (pe[e] > pe[e0]) e0 = e;
    int e1 = -1;
    for (int e = 0; e < NE; e++) {
      if (e == e0) continue;
      if (e1 < 0 || pe[e] > pe[e1]) e1 = e;
    }
    float wsum = pe[e0] + pe[e1];
    selbuf[t * 2] = e0; selbuf[t * 2 + 1] = e1;
    wbuf[t * 2] = pe[e0] / wsum; wbuf[t * 2 + 1] = pe[e1] / wsum;
    atomicAdd(&cnt[e0], 1);
    atomicAdd(&cnt[e1], 1);
  }
}

__global__ __launch_bounds__(256)
void prob_reduce(const float* __restrict__ probbuf, float* __restrict__ prob_sum, int rows) {
  int e = blockIdx.x, tid = threadIdx.x;
  float s = 0.f;
  for (int t = tid; t < rows; t += 256) s += probbuf[(size_t)t * NE + e];
  __shared__ float red[256];
  red[tid] = s;
  __syncthreads();
  for (int k = 128; k > 0; k >>= 1) { if (tid < k) red[tid] += red[tid + k]; __syncthreads(); }
  if (tid == 0) prob_sum[e] = red[0];
}

__global__ void scan_bal(const int* __restrict__ cnt, int* __restrict__ off,
                         int* __restrict__ fill, const float* __restrict__ prob_sum,
                         float* __restrict__ bal, int rows) {
  if (threadIdx.x == 0 && blockIdx.x == 0) {
    int acc = 0;
    for (int e = 0; e < NE; e++) { off[e] = acc; acc += cnt[e]; fill[e] = 0; }
    off[NE] = acc;
    float invr = 1.f / (float)rows;
    float b = 0.f;
    for (int e = 0; e < NE; e++) b += (prob_sum[e] * invr) * ((float)cnt[e] * invr);
    bal[0] += (float)NE * b;
  }
}

__global__ void fill_kernel(const int* __restrict__ selbuf, const float* __restrict__ wbuf,
                            const int* __restrict__ off, int* __restrict__ fill,
                            int* __restrict__ perm, float* __restrict__ wlist, int rows) {
  int t = blockIdx.x * blockDim.x + threadIdx.x;
  if (t >= rows) return;
  for (int k = 0; k < 2; k++) {
    int e = selbuf[t * 2 + k];
    int pos = atomicAdd(&fill[e], 1);
    perm[off[e] + pos] = t;
    wlist[off[e] + pos] = wbuf[t * 2 + k];
  }
}

// ---------------- global-path assembly ----------------
__global__ void build_gin(const float* __restrict__ X, const float* __restrict__ latent,
                          float* __restrict__ G) {
  int i = blockIdx.x * blockDim.x + threadIdx.x;
  if (i >= S1R * DD) return;
  int r = i / DD, d = i - r * DD;
  G[i] = (r == 0) ? latent[d] : X[(size_t)((r - 1) * 16 + 15) * DD + d];
}

__global__ void compose_kernel(const float* __restrict__ X, const float* __restrict__ G,
                               float* __restrict__ F) {
  int i = blockIdx.x * blockDim.x + threadIdx.x;
  if (i >= TT * DD) return;
  int t = i / DD, d = i - t * DD;
  F[i] = X[i] + G[(size_t)(t >> 4) * DD + d];
}

__global__ void write_bal(const float* __restrict__ bal, float* __restrict__ out) {
  if (threadIdx.x == 0 && blockIdx.x == 0) out[(size_t)TT * NV] = bal[0];
}

// ---------------- host launch ----------------
extern "C" void kernel_launch(void* const* d_in, const int* in_sizes, int n_in,
                              void* d_out, int out_size, void* d_ws, size_t ws_size,
                              hipStream_t stream) {
  (void)in_sizes; (void)n_in; (void)out_size; (void)ws_size;
  const float* x_emb    = (const float*)d_in[0];
  const float* latent   = (const float*)d_in[1];
  const float* pos_emb  = (const float*)d_in[2];
  const float* loc_ln1_s = (const float*)d_in[3];
  const float* loc_ln1_b = (const float*)d_in[4];
  const float* loc_ln2_s = (const float*)d_in[5];
  const float* loc_ln2_b = (const float*)d_in[6];
  const float* loc_aw    = (const float*)d_in[7];
  const float* loc_ab    = (const float*)d_in[8];
  const float* loc_ow    = (const float*)d_in[9];
  const float* loc_ob    = (const float*)d_in[10];
  const float* loc_rw    = (const float*)d_in[11];
  const float* loc_w1    = (const float*)d_in[12];
  const float* loc_b1    = (const float*)d_in[13];
  const float* loc_w2    = (const float*)d_in[14];
  const float* loc_b2    = (const float*)d_in[15];
  const float* glb_ln1_s = (const float*)d_in[16];
  const float* glb_ln1_b = (const float*)d_in[17];
  const float* glb_ln2_s = (const float*)d_in[18];
  const float* glb_ln2_b = (const float*)d_in[19];
  const float* glb_aw    = (const float*)d_in[20];
  const float* glb_ab    = (const float*)d_in[21];
  const float* glb_ow    = (const float*)d_in[22];
  const float* glb_ob    = (const float*)d_in[23];
  const float* glb_rw    = (const float*)d_in[24];
  const float* glb_w1    = (const float*)d_in[25];
  const float* glb_b1    = (const float*)d_in[26];
  const float* glb_w2    = (const float*)d_in[27];
  const float* glb_b2    = (const float*)d_in[28];
  const float* glb_lrw   = (const float*)d_in[29];
  const float* ln_s      = (const float*)d_in[30];
  const float* ln_b      = (const float*)d_in[31];
  const float* head_w    = (const float*)d_in[32];
  float* out = (float*)d_out;

  // workspace layout (floats)
  float* base = (float*)d_ws;
  float* X    = base;
  float* Hb   = X    + (size_t)TT * DD;
  float* QKV  = Hb   + (size_t)TT * DD;
  float* ATTO = QKV  + (size_t)TT * QKVLD;
  float* H1   = ATTO + (size_t)TT * DD;
  float* G    = H1   + (size_t)4096 * DFF;
  float* PROB = G    + (size_t)S1R * DD;
  float* WL   = PROB + (size_t)TT * NE;
  float* WB   = WL   + 4096;
  float* PS   = WB   + (size_t)TT * 2;
  float* BAL  = PS   + 16;
  int*   SEL  = (int*)(BAL + 16);
  int*   PERM = SEL  + 2 * TT;
  int*   CNT  = PERM + 4096;
  int*   FILL = CNT  + 16;
  int*   OFFP = FILL + 16;

  auto run_layer = [&](float* Xp, int rows,
                       const float* l1s, const float* l1b,
                       const float* l2s, const float* l2b,
                       const float* aw, const float* ab,
                       const float* ow, const float* ob,
                       const float* rw, const float* w1, const float* b1,
                       const float* w2, const float* b2,
                       const float* lat, const float* lrw) {
    int mg = (rows + BM - 1) / BM;
    ln_kernel<<<rows, 256, 0, stream>>>(Xp, l1s, l1b, Hb, rows);
    gemm_tn<false><<<dim3(QKVLD / BN, mg), 256, 0, stream>>>(Hb, aw, ab, QKV, rows, QKVLD, DD);
    attn_kernel<<<dim3(rows, NH), 64, 0, stream>>>(QKV, ATTO, rows);
    gemm_tn<true><<<dim3(DD / BN, mg), 256, 0, stream>>>(ATTO, ow, ob, Xp, rows, DD, DD);
    ln_kernel<<<rows, 256, 0, stream>>>(Xp, l2s, l2b, Hb, rows);
    zero_i32<<<1, 32, 0, stream>>>(CNT, 16);
    router_kernel<<<rows, 64, 0, stream>>>(Hb, rw, lat, lrw, rows, SEL, WB, PROB, CNT);
    prob_reduce<<<NE, 256, 0, stream>>>(PROB, PS, rows);
    scan_bal<<<1, 64, 0, stream>>>(CNT, OFFP, FILL, PS, BAL, rows);
    fill_kernel<<<(rows + 255) / 256, 256, 0, stream>>>(SEL, WB, OFFP, FILL, PERM, WL, rows);
    moe_gemm1<<<dim3(DFF / BN, mg, NE), 256, 0, stream>>>(Hb, w1, b1, H1, PERM, OFFP);
    moe_gemm2<<<dim3(DD / BN, mg, NE), 256, 0, stream>>>(H1, w2, b2, Xp, PERM, OFFP, WL);
  };

  // x = x_emb + pos_emb
  add_pos_kernel<<<(TT * DD + 255) / 256, 256, 0, stream>>>(x_emb, pos_emb, X, TT * DD);
  zero_f32<<<1, 32, 0, stream>>>(BAL, 1);

  // local layers
  for (int l = 0; l < 2; l++) {
    run_layer(X, TT,
              loc_ln1_s + (size_t)l * DD, loc_ln1_b + (size_t)l * DD,
              loc_ln2_s + (size_t)l * DD, loc_ln2_b + (size_t)l * DD,
              loc_aw + (size_t)l * QKVLD * DD, loc_ab + (size_t)l * QKVLD,
              loc_ow + (size_t)l * DD * DD, loc_ob + (size_t)l * DD,
              loc_rw + (size_t)l * NE * DD,
              loc_w1 + (size_t)l * NE * DFF * DD, loc_b1 + (size_t)l * NE * DFF,
              loc_w2 + (size_t)l * NE * DD * DFF, loc_b2 + (size_t)l * NE * DD,
              nullptr, nullptr);
  }

  // global path
  build_gin<<<(S1R * DD + 255) / 256, 256, 0, stream>>>(X, latent, G);
  run_layer(G, S1R,
            glb_ln1_s, glb_ln1_b, glb_ln2_s, glb_ln2_b,
            glb_aw, glb_ab, glb_ow, glb_ob,
            glb_rw, glb_w1, glb_b1, glb_w2, glb_b2,
            latent, glb_lrw);

  // compose + final LN + head (bf16 MFMA)
  float* Fbuf = QKV;   // reuse
  float* FN   = ATTO;  // reuse
  compose_kernel<<<(TT * DD + 255) / 256, 256, 0, stream>>>(X, G, Fbuf);
  ln_kernel<<<TT, 256, 0, stream>>>(Fbuf, ln_s, ln_b, FN, TT);

  // bf16 casts into now-free workspace: A->Hb region, W->H1 region
  ushort* Abf = (ushort*)Hb;   // needs 2048*768*2B = 3.1 MB  (< 6.3 MB avail)
  ushort* Wbf = (ushort*)H1;   // needs 32000*768*2B = 49.2 MB (< 50.3 MB avail)
  cast_bf16_kernel<<<(TT * DD / 4 + 255) / 256, 256, 0, stream>>>(FN, Abf, TT * DD);
  cast_bf16_kernel<<<(NV * DD / 4 + 255) / 256, 256, 0, stream>>>(head_w, Wbf, NV * DD);
  head_gemm_bf16<<<dim3(NV / 128, TT / 128), 256, 0, stream>>>(Abf, Wbf, out, TT, NV, DD);

  write_bal<<<1, 1, 0, stream>>>(BAL, out);
}